// Round 12
// baseline (365.066 us; speedup 1.0000x reference)
//
#include <hip/hip_runtime.h>
#include <hip/hip_bf16.h>

#define N_NODES 100000
#define N_EDGES 1600000
#define F_IN 128
#define HID 64
#define SCAN_NB 98   // ceil(100000/1024) — grid for detect
#define NBUCK 391    // ceil(100000/256) column buckets
#define BSH 8        // 256 nodes per bucket
#define NSCB 784     // blocks for count/scatter passes (2x round-11 for occupancy)

typedef __attribute__((ext_vector_type(8))) short short8;
typedef __attribute__((ext_vector_type(2))) float vf2;

__device__ __forceinline__ float bfbits2f(unsigned short u) {
    union { unsigned int i; float f; } v;
    v.i = ((unsigned int)u) << 16;
    return v.f;
}
__device__ __forceinline__ unsigned short f2bfbits(float f) {
    union { float f; unsigned int i; } v;
    v.f = f;
    unsigned int r = v.i + 0x7FFFu + ((v.i >> 16) & 1u);  // RNE
    return (unsigned short)(r >> 16);
}
__device__ __forceinline__ unsigned int pack2bf(float a, float b) {
    return ((unsigned int)f2bfbits(b) << 16) | (unsigned int)f2bfbits(a);
}
__device__ __forceinline__ float lo_bf(unsigned int w) { return bfbits2f((unsigned short)(w & 0xFFFF)); }
__device__ __forceinline__ float hi_bf(unsigned int w) { return bfbits2f((unsigned short)(w >> 16)); }
// unpack u32 (2 packed bf16) -> float2: {lo<<16, hi&mask} reinterpreted. 2 VALU ops for 2 channels.
__device__ __forceinline__ vf2 unpack_bf2(unsigned int w) {
    union { unsigned int i[2]; vf2 f; } u;
    u.i[0] = w << 16;
    u.i[1] = w & 0xFFFF0000u;
    return u.f;
}

// ---- detect flags AND zero bucket counters; block 0 does flag logic ----
__global__ void k_detect(const int* __restrict__ ei, const unsigned int* __restrict__ x32,
                         int* __restrict__ flag, int* __restrict__ gcount) {
    int gid = blockIdx.x * 1024 + threadIdx.x;
    if (gid < NBUCK) gcount[gid] = 0;
    if (blockIdx.x != 0) return;
    __shared__ int s_odd, s_cnt;
    if (threadIdx.x == 0) { s_odd = 0; s_cnt = 0; }
    __syncthreads();
    int t = threadIdx.x;  // 1024 threads
    if (ei[2 * t + 1] != 0) atomicOr(&s_odd, 1);
    if (t < 256) {
        unsigned int u = x32[t];
        unsigned int e = (u >> 7) & 0xFF;
        if (e >= 0x68 && e <= 0x97) atomicAdd(&s_cnt, 1);
    }
    __syncthreads();
    if (t == 0) {
        flag[0] = (s_odd == 0) ? 1 : 0;
        flag[1] = (s_cnt >= 160) ? 1 : 0;
    }
}

__device__ __forceinline__ int clampN(int v) {
    v = v < 0 ? 0 : v;
    return v > (N_NODES - 1) ? (N_NODES - 1) : v;
}
__device__ __forceinline__ int load_row(const int* __restrict__ ei, int f, int e) {
    return clampN(f ? ei[2 * e] : ei[e]);
}
__device__ __forceinline__ int load_col(const int* __restrict__ ei, int f, int e) {
    return clampN(f ? ei[2 * (N_EDGES + e)] : ei[N_EDGES + e]);
}

// ---- fp32 weight scratch layout (floats) ----
#define WF_W1   0
#define WF_W2   8192
#define WF_L1W  12288
#define WF_B1   20480
#define WF_B2   20544
#define WF_L1B  20608
#define WF_L2W  20672
#define WF_L2B  20800
#define WF_TOT  20802

__global__ void k_prep(const void* W1, const void* W2, const void* L1W,
                       const void* b1, const void* b2, const void* L1b,
                       const void* L2W, const void* L2b,
                       const int* __restrict__ flag, float* __restrict__ Wf) {
    int idx = blockIdx.x * blockDim.x + threadIdx.x;
    if (idx >= WF_TOT) return;
    int bf = flag[1];
    const void* src; int k;
    if      (idx < WF_W2)  { src = W1;  k = idx; }
    else if (idx < WF_L1W) { src = W2;  k = idx - WF_W2; }
    else if (idx < WF_B1)  { src = L1W; k = idx - WF_L1W; }
    else if (idx < WF_B2)  { src = b1;  k = idx - WF_B1; }
    else if (idx < WF_L1B) { src = b2;  k = idx - WF_B2; }
    else if (idx < WF_L2W) { src = L1b; k = idx - WF_L1B; }
    else if (idx < WF_L2B) { src = L2W; k = idx - WF_L2W; }
    else                   { src = L2b; k = idx - WF_L2B; }
    Wf[idx] = bf ? bfbits2f(((const unsigned short*)src)[k]) : ((const float*)src)[k];
}

// ===== bucketed CSR build (deterministic, no global cursor atomics) =====

// ---- pass 1: LDS histogram; emit per-block hist matrix + global bucket counts ----
__global__ void __launch_bounds__(256) k_bcount(const int* __restrict__ ei,
                                                const int* __restrict__ flag,
                                                int* __restrict__ gcount,
                                                int* __restrict__ bhist) {
    __shared__ int hist[NBUCK];
    for (int t = threadIdx.x; t < NBUCK; t += 256) hist[t] = 0;
    __syncthreads();
    int f = flag[0];
    const int EPB = (N_EDGES + NSCB - 1) / NSCB;
    int base = blockIdx.x * EPB;
    int end = base + EPB; if (end > N_EDGES) end = N_EDGES;
    for (int e = base + threadIdx.x; e < end; e += 256)
        atomicAdd(&hist[load_col(ei, f, e) >> BSH], 1);
    __syncthreads();
    for (int t = threadIdx.x; t < NBUCK; t += 256) {
        int hv = hist[t];
        bhist[(size_t)blockIdx.x * NBUCK + t] = hv;   // coalesced
        if (hv) atomicAdd(&gcount[t], hv);
    }
}

// ---- pass 2 (fused): block b scans the 391 bucket totals itself (writes bbase[b]),
// then scans its bucket's per-block column (784 wide) -> bofs[b][blk]. ----
__global__ void __launch_bounds__(1024) k_bscan2(const int* __restrict__ gcount,
                                                 const int* __restrict__ bhist,
                                                 int* __restrict__ bbase,
                                                 int* __restrict__ bofs,
                                                 int* __restrict__ rowptr) {
    __shared__ int s[1024];
    __shared__ int bb;
    int b = blockIdx.x;
    int t = threadIdx.x;
    // scan bucket totals -> this bucket's global base
    int v = (t < NBUCK) ? gcount[t] : 0;
    s[t] = v; __syncthreads();
    for (int off = 1; off < 1024; off <<= 1) {
        int add = (t >= off) ? s[t - off] : 0;
        __syncthreads();
        s[t] += add;
        __syncthreads();
    }
    if (t == b) { bb = s[t] - v; bbase[b] = bb; }
    if (b == 0 && t == 0) { bbase[NBUCK] = N_EDGES; rowptr[N_NODES] = N_EDGES; }
    __syncthreads();
    int base_b = bb;
    // per-(block,bucket) exact bases for bucket b
    int v2 = (t < NSCB) ? bhist[(size_t)t * NBUCK + b] : 0;
    s[t] = v2; __syncthreads();
    for (int off = 1; off < 1024; off <<= 1) {
        int add = (t >= off) ? s[t - off] : 0;
        __syncthreads();
        s[t] += add;
        __syncthreads();
    }
    if (t < NSCB) bofs[(size_t)b * NSCB + t] = base_b + s[t] - v2;  // coalesced
}

// ---- pass 3: LDS bucket-sort, then MONOTONE global writes (lbase[b] ascending in b)
// EPB=2041 -> ~24 KB LDS, 512 threads, 784 blocks (~3 blocks/CU) ----
__global__ void __launch_bounds__(512) k_bscatter(const int* __restrict__ ei,
                                                  const int* __restrict__ flag,
                                                  const int* __restrict__ bofs,
                                                  unsigned int* __restrict__ tmp) {
    __shared__ unsigned int sortedv[2048];  // EPB=2041 padded
    __shared__ int sorteda[2048];
    __shared__ int lbase[NBUCK];
    __shared__ int hist[NBUCK];
    __shared__ int lofs[NBUCK];
    __shared__ int s[512];
    int t = threadIdx.x;
    for (int i = t; i < NBUCK; i += 512) {
        lbase[i] = bofs[(size_t)i * NSCB + blockIdx.x];
        hist[i] = 0;
    }
    __syncthreads();
    int f = flag[0];
    const int EPB = (N_EDGES + NSCB - 1) / NSCB;
    int base = blockIdx.x * EPB;
    int end = base + EPB; if (end > N_EDGES) end = N_EDGES;
    for (int e = base + t; e < end; e += 512)
        atomicAdd(&hist[load_col(ei, f, e) >> BSH], 1);
    __syncthreads();
    int v = (t < NBUCK) ? hist[t] : 0;
    s[t] = v; __syncthreads();
    for (int off = 1; off < 512; off <<= 1) {
        int add = (t >= off) ? s[t - off] : 0;
        __syncthreads();
        s[t] += add;
        __syncthreads();
    }
    if (t < NBUCK) { lofs[t] = s[t] - v; hist[t] = 0; }  // hist becomes rank cursor
    __syncthreads();
    for (int e = base + t; e < end; e += 512) {           // ei re-read is L2-warm
        int r = load_row(ei, f, e), c = load_col(ei, f, e);
        int b = c >> BSH;
        int rk = atomicAdd(&hist[b], 1);
        int sp = lofs[b] + rk;
        sortedv[sp] = ((unsigned int)r << BSH) | (unsigned int)(c & 255);
        sorteda[sp] = lbase[b] + rk;
    }
    __syncthreads();
    int cnt = end - base;
    for (int i = t; i < cnt; i += 512)
        tmp[sorteda[i]] = sortedv[i];
}

// ---- pass 4: per-bucket sub-CSR entirely in LDS (emits csr_src, rowptr, dinv).
// 256 nodes/bucket, one node per thread. ----
__global__ void __launch_bounds__(256) k_bcsr(const unsigned int* __restrict__ tmp,
                                              const int* __restrict__ bbase,
                                              int* __restrict__ rowptr,
                                              float* __restrict__ dinv,
                                              int* __restrict__ csr_src) {
    __shared__ int nh[256];    // per-node counts (stable after count phase)
    __shared__ int nrp[256];   // inclusive prefix
    __shared__ int ncur[256];  // placement cursor
    int nb = blockIdx.x;
    int s0 = bbase[nb], s1 = bbase[nb + 1];
    int cnt = s1 - s0;
    int t = threadIdx.x;
    nh[t] = 0; ncur[t] = 0;
    __syncthreads();
    for (int i = t; i < cnt; i += 256)
        atomicAdd(&nh[tmp[s0 + i] & 255], 1);
    __syncthreads();
    nrp[t] = nh[t];
    __syncthreads();
    for (int off = 1; off < 256; off <<= 1) {
        int add = (t >= off) ? nrp[t - off] : 0;
        __syncthreads();
        nrp[t] += add;
        __syncthreads();
    }
    int nodeBase = nb * 256;
    if (nodeBase + t < N_NODES) {
        rowptr[nodeBase + t] = s0 + nrp[t] - nh[t];  // exclusive prefix
        dinv[nodeBase + t] = rsqrtf((float)(nh[t] + 1));
    }
    __syncthreads();
    for (int i = t; i < cnt; i += 256) {
        unsigned int v = tmp[s0 + i];
        int cl = v & 255;
        int rk = atomicAdd(&ncur[cl], 1);
        csr_src[s0 + (nrp[cl] - nh[cl]) + rk] = (int)(v >> BSH);
    }
}

// ===== node tables: packed bf16 rows, 32 u32 (=64 ch) per node =====
// packed-f32 inner loop: acc as vf2[16], weight rows as vf2 pairs, scalar x
// broadcast -> v_pk_fma_f32 halves VALU issue count
__device__ __forceinline__ void fma8_32p(const float* xv, const float* __restrict__ W,
                                         int k0, int coloff, vf2* acc) {
#pragma unroll
    for (int t = 0; t < 8; t++) {
        const vf2* wr = (const vf2*)(W + (k0 + t) * 64 + coloff);
        vf2 xb = {xv[t], xv[t]};
#pragma unroll
        for (int j = 0; j < 16; j++) acc[j] += xb * wr[j];
    }
}

// ---- layer-1 GEMM (wave-split): x [N,128] @ Wf[128,64] -> bufA bf16; scale=dinv ----
__global__ void __launch_bounds__(256) k_gemm_in_ws(const void* __restrict__ x,
                                                    const float* __restrict__ Wf,
                                                    const float* __restrict__ dinv,
                                                    unsigned int* __restrict__ hs,
                                                    const int* __restrict__ flag) {
    int wv = __builtin_amdgcn_readfirstlane(threadIdx.x >> 6);  // 0..3, scalar
    int wid = blockIdx.x * 4 + wv;
    int group = wid >> 1;
    int half = wid & 1;          // scalar: col-half
    int lane = threadIdx.x & 63;
    int node = group * 64 + lane;
    if (node >= N_NODES) return;
    int bf = flag[1];
    int coloff = half * 32;
    vf2 acc[16];
#pragma unroll
    for (int j = 0; j < 16; j++) acc[j] = (vf2){0.f, 0.f};
    if (bf) {
        const unsigned short* xp = (const unsigned short*)x + (size_t)node * F_IN;
#pragma unroll 2
        for (int k0 = 0; k0 < F_IN; k0 += 8) {
            short8 raw = *(const short8*)(xp + k0);
            float xv[8];
#pragma unroll
            for (int t = 0; t < 8; t++) xv[t] = bfbits2f((unsigned short)raw[t]);
            fma8_32p(xv, Wf, k0, coloff, acc);
        }
    } else {
        const float* xp = (const float*)x + (size_t)node * F_IN;
#pragma unroll 2
        for (int k0 = 0; k0 < F_IN; k0 += 8) {
            float4 a = *(const float4*)(xp + k0);
            float4 b = *(const float4*)(xp + k0 + 4);
            float xv[8] = {a.x, a.y, a.z, a.w, b.x, b.y, b.z, b.w};
            fma8_32p(xv, Wf, k0, coloff, acc);
        }
    }
    float s = dinv[node];
    unsigned int* op = hs + (size_t)node * 32 + half * 16;
#pragma unroll
    for (int j = 0; j < 16; j++) op[j] = pack2bf(acc[j].x * s, acc[j].y * s);
}

// ---- FUSED agg1 + gemm64: gather bufA -> relu(fma(a,dinv,B1)) row in LDS ->
// (row @ W2) * dinv -> bufB. Kills the h round-trip (25.6 MB) + one launch.
// LDS row stride 33 u32 (padding -> conflict-free phase-2 reads). ----
__global__ void __launch_bounds__(256) k_aggemm(const unsigned int* __restrict__ hs,
                                                const int* __restrict__ rowptr,
                                                const int* __restrict__ csr_src,
                                                const float* __restrict__ dinv,
                                                const float* __restrict__ bias,  // B1
                                                const float* __restrict__ W2,    // [64][64]
                                                unsigned int* __restrict__ out) {
    __shared__ unsigned int hrow[16 * 33];
    int t = threadIdx.x;
    int wave = t >> 6, lane = t & 63;
    int q = lane >> 4, w = lane & 15;
    int nl = wave * 4 + q;                  // node-local 0..15
    int node = blockIdx.x * 16 + nl;        // grid 6250*16 = 100000 exactly
    // phase 1: aggregate (identical math to round-11 k_agg)
    const uint2* hp = (const uint2*)hs;
    uint2 sw = hp[(size_t)node * 16 + w];
    vf2 aA = unpack_bf2(sw.x), aB = unpack_bf2(sw.y);
    int k = rowptr[node], k1 = rowptr[node + 1];
    for (; k + 7 < k1; k += 8) {
        int s0 = csr_src[k],     s1 = csr_src[k + 1], s2 = csr_src[k + 2], s3 = csr_src[k + 3];
        int s4 = csr_src[k + 4], s5 = csr_src[k + 5], s6 = csr_src[k + 6], s7 = csr_src[k + 7];
        uint2 w0 = hp[(size_t)s0 * 16 + w];
        uint2 w1 = hp[(size_t)s1 * 16 + w];
        uint2 w2 = hp[(size_t)s2 * 16 + w];
        uint2 w3 = hp[(size_t)s3 * 16 + w];
        uint2 w4 = hp[(size_t)s4 * 16 + w];
        uint2 w5 = hp[(size_t)s5 * 16 + w];
        uint2 w6 = hp[(size_t)s6 * 16 + w];
        uint2 w7 = hp[(size_t)s7 * 16 + w];
        aA += ((unpack_bf2(w0.x) + unpack_bf2(w1.x)) + (unpack_bf2(w2.x) + unpack_bf2(w3.x)))
            + ((unpack_bf2(w4.x) + unpack_bf2(w5.x)) + (unpack_bf2(w6.x) + unpack_bf2(w7.x)));
        aB += ((unpack_bf2(w0.y) + unpack_bf2(w1.y)) + (unpack_bf2(w2.y) + unpack_bf2(w3.y)))
            + ((unpack_bf2(w4.y) + unpack_bf2(w5.y)) + (unpack_bf2(w6.y) + unpack_bf2(w7.y)));
    }
    for (; k + 3 < k1; k += 4) {
        int s0 = csr_src[k], s1 = csr_src[k + 1], s2 = csr_src[k + 2], s3 = csr_src[k + 3];
        uint2 w0 = hp[(size_t)s0 * 16 + w];
        uint2 w1 = hp[(size_t)s1 * 16 + w];
        uint2 w2 = hp[(size_t)s2 * 16 + w];
        uint2 w3 = hp[(size_t)s3 * 16 + w];
        aA += (unpack_bf2(w0.x) + unpack_bf2(w1.x)) + (unpack_bf2(w2.x) + unpack_bf2(w3.x));
        aB += (unpack_bf2(w0.y) + unpack_bf2(w1.y)) + (unpack_bf2(w2.y) + unpack_bf2(w3.y));
    }
    for (; k < k1; k++) {
        uint2 w0 = hp[(size_t)csr_src[k] * 16 + w];
        aA += unpack_bf2(w0.x);
        aB += unpack_bf2(w0.y);
    }
    float di = dinv[node];
    vf2 b0 = *(const vf2*)(bias + 4 * w);
    vf2 b1 = *(const vf2*)(bias + 4 * w + 2);
    float v0 = fmaxf(fmaf(aA.x, di, b0.x), 0.f);
    float v1 = fmaxf(fmaf(aA.y, di, b0.y), 0.f);
    float v2 = fmaxf(fmaf(aB.x, di, b1.x), 0.f);
    float v3 = fmaxf(fmaf(aB.y, di, b1.y), 0.f);
    hrow[nl * 33 + 2 * w]     = pack2bf(v0, v1);
    hrow[nl * 33 + 2 * w + 1] = pack2bf(v2, v3);
    __syncthreads();
    // phase 2: gemm64 from LDS. thread t: node n2=t>>4, out channels 4cg..4cg+3.
    // Lanes 0..15 share n2 (LDS broadcast) and read consecutive weight chunks (coalesced).
    int n2 = t >> 4, cg = t & 15;
    int node2 = blockIdx.x * 16 + n2;
    const unsigned int* hr = &hrow[n2 * 33];
    vf2 a0 = {0.f, 0.f}, a1 = {0.f, 0.f};
#pragma unroll
    for (int m = 0; m < 32; m++) {
        vf2 xk = unpack_bf2(hr[m]);
        const vf2* wr0 = (const vf2*)(W2 + (2 * m) * 64 + 4 * cg);
        const vf2* wr1 = (const vf2*)(W2 + (2 * m + 1) * 64 + 4 * cg);
        a0 += xk.x * wr0[0]; a1 += xk.x * wr0[1];
        a0 += xk.y * wr1[0]; a1 += xk.y * wr1[1];
    }
    float s2 = dinv[node2];
    uint2 ow; ow.x = pack2bf(a0.x * s2, a0.y * s2); ow.y = pack2bf(a1.x * s2, a1.y * s2);
    *(uint2*)(out + (size_t)node2 * 32 + 2 * cg) = ow;
}

// ---- edge-MLP projections (wave-split, 4 tasks): block = 64 nodes x 4 waves ----
__global__ void __launch_bounds__(256) k_pair_ws(unsigned int* __restrict__ h,
                                                 const float* __restrict__ W,  // L1W [128][64]
                                                 unsigned int* __restrict__ P1) {
    int task = __builtin_amdgcn_readfirstlane(threadIdx.x >> 6);  // 0..3, scalar
    int lane = threadIdx.x & 63;
    int node = blockIdx.x * 64 + lane;
    bool valid = node < N_NODES;
    int coloff = (task & 1) * 32;
    const float* Wb = W + (task >> 1) * 64 * 64;  // k-row base: P1 rows 0.., P2 rows 64..
    vf2 acc[16];
#pragma unroll
    for (int j = 0; j < 16; j++) acc[j] = (vf2){0.f, 0.f};
    if (valid) {
        const unsigned short* hp = (const unsigned short*)(h + (size_t)node * 32);
#pragma unroll 2
        for (int k0 = 0; k0 < 64; k0 += 8) {
            short8 raw = *(const short8*)(hp + k0);
            float xv[8];
#pragma unroll
            for (int t = 0; t < 8; t++) xv[t] = bfbits2f((unsigned short)raw[t]);
            fma8_32p(xv, Wb, k0, coloff, acc);
        }
    }
    __syncthreads();  // all reads of this block's 64 h-rows complete before P2 writes
    if (valid) {
        unsigned int* op = (task < 2 ? P1 : h) + (size_t)node * 32 + coloff / 2;
#pragma unroll
        for (int j = 0; j < 16; j++) op[j] = pack2bf(acc[j].x, acc[j].y);
    }
}

// ---- agg2: wave = 4 nodes; 16 lanes/node; uint2 gathers; x8 unroll ----
__global__ void __launch_bounds__(256) k_agg(const unsigned int* __restrict__ hs,
                                             const int* __restrict__ rowptr,
                                             const int* __restrict__ csr_src,
                                             const float* __restrict__ dinv,
                                             const float* __restrict__ bias,
                                             unsigned int* __restrict__ h) {
    int wid = blockIdx.x * 4 + (threadIdx.x >> 6);
    int lane = threadIdx.x & 63;
    int q = lane >> 4;          // node within wave (0..3)
    int w = lane & 15;          // uint2 index within row: channels 4w..4w+3
    int node = wid * 4 + q;
    if (node >= N_NODES) return;
    const uint2* hp = (const uint2*)hs;  // row = 16 uint2
    uint2 sw = hp[(size_t)node * 16 + w];
    vf2 aA = unpack_bf2(sw.x), aB = unpack_bf2(sw.y);
    int k = rowptr[node], k1 = rowptr[node + 1];
    for (; k + 7 < k1; k += 8) {
        int s0 = csr_src[k],     s1 = csr_src[k + 1], s2 = csr_src[k + 2], s3 = csr_src[k + 3];
        int s4 = csr_src[k + 4], s5 = csr_src[k + 5], s6 = csr_src[k + 6], s7 = csr_src[k + 7];
        uint2 w0 = hp[(size_t)s0 * 16 + w];
        uint2 w1 = hp[(size_t)s1 * 16 + w];
        uint2 w2 = hp[(size_t)s2 * 16 + w];
        uint2 w3 = hp[(size_t)s3 * 16 + w];
        uint2 w4 = hp[(size_t)s4 * 16 + w];
        uint2 w5 = hp[(size_t)s5 * 16 + w];
        uint2 w6 = hp[(size_t)s6 * 16 + w];
        uint2 w7 = hp[(size_t)s7 * 16 + w];
        aA += ((unpack_bf2(w0.x) + unpack_bf2(w1.x)) + (unpack_bf2(w2.x) + unpack_bf2(w3.x)))
            + ((unpack_bf2(w4.x) + unpack_bf2(w5.x)) + (unpack_bf2(w6.x) + unpack_bf2(w7.x)));
        aB += ((unpack_bf2(w0.y) + unpack_bf2(w1.y)) + (unpack_bf2(w2.y) + unpack_bf2(w3.y)))
            + ((unpack_bf2(w4.y) + unpack_bf2(w5.y)) + (unpack_bf2(w6.y) + unpack_bf2(w7.y)));
    }
    for (; k + 3 < k1; k += 4) {
        int s0 = csr_src[k], s1 = csr_src[k + 1], s2 = csr_src[k + 2], s3 = csr_src[k + 3];
        uint2 w0 = hp[(size_t)s0 * 16 + w];
        uint2 w1 = hp[(size_t)s1 * 16 + w];
        uint2 w2 = hp[(size_t)s2 * 16 + w];
        uint2 w3 = hp[(size_t)s3 * 16 + w];
        aA += (unpack_bf2(w0.x) + unpack_bf2(w1.x)) + (unpack_bf2(w2.x) + unpack_bf2(w3.x));
        aB += (unpack_bf2(w0.y) + unpack_bf2(w1.y)) + (unpack_bf2(w2.y) + unpack_bf2(w3.y));
    }
    for (; k < k1; k++) {
        uint2 w0 = hp[(size_t)csr_src[k] * 16 + w];
        aA += unpack_bf2(w0.x);
        aB += unpack_bf2(w0.y);
    }
    float di = dinv[node];
    vf2 b0 = *(const vf2*)(bias + 4 * w);
    vf2 b1 = *(const vf2*)(bias + 4 * w + 2);
    float v0 = fmaxf(fmaf(aA.x, di, b0.x), 0.f);
    float v1 = fmaxf(fmaf(aA.y, di, b0.y), 0.f);
    float v2 = fmaxf(fmaf(aB.x, di, b1.x), 0.f);
    float v3 = fmaxf(fmaf(aB.y, di, b1.y), 0.f);
    uint2 ow; ow.x = pack2bf(v0, v1); ow.y = pack2bf(v2, v3);
    *(uint2*)(h + (size_t)node * 32 + 2 * w) = ow;
}

// ---- edge MLP: 8 lanes per edge-quad, direct per-lane index loads, packed-f32
// channel math (measured: 53.0 µs, VGPR 36, occupancy 61%) ----
__global__ void __launch_bounds__(256) k_edge(const int* __restrict__ ei,
                       const unsigned int* __restrict__ P1, const unsigned int* __restrict__ P2,
                       const float* __restrict__ Wf, const int* __restrict__ flag,
                       void* __restrict__ out) {
    int tid = blockIdx.x * 256 + threadIdx.x;
    int g = tid >> 3;       // quad index: edges 4g .. 4g+3
    int k = tid & 7;        // sub-lane: channels j = 8k .. 8k+7
    int e0 = g * 4;
    if (e0 >= N_EDGES) return;  // N_EDGES % 4 == 0 -> e0..e0+3 all valid
    int f = flag[0];
    int r0 = load_row(ei, f, e0),     c0 = load_col(ei, f, e0);
    int r1 = load_row(ei, f, e0 + 1), c1 = load_col(ei, f, e0 + 1);
    int r2 = load_row(ei, f, e0 + 2), c2 = load_col(ei, f, e0 + 2);
    int r3 = load_row(ei, f, e0 + 3), c3 = load_col(ei, f, e0 + 3);
    // issue all 8 gathers before any compute
    uint4 ua0 = *(const uint4*)(P1 + (size_t)r0 * 32 + k * 4);
    uint4 ub0 = *(const uint4*)(P2 + (size_t)c0 * 32 + k * 4);
    uint4 ua1 = *(const uint4*)(P1 + (size_t)r1 * 32 + k * 4);
    uint4 ub1 = *(const uint4*)(P2 + (size_t)c1 * 32 + k * 4);
    uint4 ua2 = *(const uint4*)(P1 + (size_t)r2 * 32 + k * 4);
    uint4 ub2 = *(const uint4*)(P2 + (size_t)c2 * 32 + k * 4);
    uint4 ua3 = *(const uint4*)(P1 + (size_t)r3 * 32 + k * 4);
    uint4 ub3 = *(const uint4*)(P2 + (size_t)c3 * 32 + k * 4);
    // bias pairs and L2-weight pairs for this lane's 8 channels
    vf2 b2[4], wp[8];
#pragma unroll
    for (int t = 0; t < 4; t++) b2[t] = *(const vf2*)(Wf + WF_L1B + k * 8 + 2 * t);
#pragma unroll
    for (int t = 0; t < 8; t++) wp[t] = *(const vf2*)(Wf + WF_L2W + k * 16 + 2 * t);
    vf2 acc[4] = {{0.f, 0.f}, {0.f, 0.f}, {0.f, 0.f}, {0.f, 0.f}};
    auto edge_mlp = [&](const uint4& ua, const uint4& ub, int i) {
        unsigned int wa[4] = {ua.x, ua.y, ua.z, ua.w};
        unsigned int wb[4] = {ub.x, ub.y, ub.z, ub.w};
#pragma unroll
        for (int t = 0; t < 4; t++) {
            vf2 z = unpack_bf2(wa[t]) + unpack_bf2(wb[t]) + b2[t];
            z = __builtin_elementwise_max(z, (vf2){0.f, 0.f});
            acc[i] += z.x * wp[2 * t];      // (s0,s1) += z_ch0 * (w00,w01)
            acc[i] += z.y * wp[2 * t + 1];  // (s0,s1) += z_ch1 * (w10,w11)
        }
    };
    edge_mlp(ua0, ub0, 0);
    edge_mlp(ua1, ub1, 1);
    edge_mlp(ua2, ub2, 2);
    edge_mlp(ua3, ub3, 3);
    float s0[4], s1[4];
#pragma unroll
    for (int i = 0; i < 4; i++) { s0[i] = acc[i].x; s1[i] = acc[i].y; }
#pragma unroll
    for (int off = 1; off < 8; off <<= 1) {
#pragma unroll
        for (int i = 0; i < 4; i++) {
            s0[i] += __shfl_xor(s0[i], off);
            s1[i] += __shfl_xor(s1[i], off);
        }
    }
    if (k == 0) {
        float b0f = Wf[WF_L2B + 0], b1f = Wf[WF_L2B + 1];
        float z0[4], z1[4];
#pragma unroll
        for (int i = 0; i < 4; i++) {
            float za = s0[i] + b0f, zb = s1[i] + b1f;
            float m = fmaxf(za, zb);
            float lse = m + __logf(__expf(za - m) + __expf(zb - m));
            z0[i] = za - lse; z1[i] = zb - lse;
        }
        if (flag[1]) {
            uint4 v;
            v.x = pack2bf(z0[0], z1[0]); v.y = pack2bf(z0[1], z1[1]);
            v.z = pack2bf(z0[2], z1[2]); v.w = pack2bf(z0[3], z1[3]);
            *(uint4*)((unsigned int*)out + e0) = v;
        } else {
            float4 v01, v23;
            v01.x = z0[0]; v01.y = z1[0]; v01.z = z0[1]; v01.w = z1[1];
            v23.x = z0[2]; v23.y = z1[2]; v23.z = z0[3]; v23.w = z1[3];
            float4* op = (float4*)((float2*)out + e0);
            op[0] = v01;
            op[1] = v23;
        }
    }
}

extern "C" void kernel_launch(void* const* d_in, const int* in_sizes, int n_in,
                              void* d_out, int out_size, void* d_ws, size_t ws_size,
                              hipStream_t stream) {
    const void* x   = d_in[0];
    const int*  ei  = (const int*)d_in[1];

    char* ws = (char*)d_ws;
    constexpr size_t KB = 1024;

    int*   gcount = (int*)(ws);                    // 391 ints
    int*   bbase  = (int*)(ws + 8 * KB);           // 392 ints
    int*   flag   = (int*)(ws + 12 * KB);          // 8 B
    float* Wf     = (float*)(ws + 16 * KB);        // 83.2 KB -> ends ~99 KB
    float* dinv   = (float*)(ws + 400 * KB);       // 400 KB
    int*   rowptr = (int*)(ws + 800 * KB);         // 400 KB + 4
    unsigned int* tmp = (unsigned int*)(ws + 1300 * KB);  // 6400 KB -> ends 7700
    int*   csrsrc = (int*)(ws + 7700 * KB);        // 6400 KB -> ends 14100
    int*   bhist  = (int*)(ws + 14100 * KB);       // 784*391*4 = 1.23 MB -> ends ~15330
    int*   bofs   = (int*)(ws + 15400 * KB);       // 1.23 MB -> ends ~16630
    unsigned int* bufA = (unsigned int*)(ws + 20500 * KB);  // 12800 KB
    unsigned int* bufB = (unsigned int*)(ws + 33300 * KB);  // 12800 KB

    // detect + bucket-counter zero fused
    k_detect<<<SCAN_NB, 1024, 0, stream>>>(ei, (const unsigned int*)x, flag, gcount);
    k_prep<<<(WF_TOT + 255) / 256, 256, 0, stream>>>(d_in[2], d_in[4], d_in[6], d_in[3],
                                                     d_in[5], d_in[7], d_in[8], d_in[9],
                                                     flag, Wf);

    // bucketed CSR build: count -> fused scans -> LDS-sorted scatter -> sub-CSR
    k_bcount<<<NSCB, 256, 0, stream>>>(ei, flag, gcount, bhist);
    k_bscan2<<<NBUCK, 1024, 0, stream>>>(gcount, bhist, bbase, bofs, rowptr);
    k_bscatter<<<NSCB, 512, 0, stream>>>(ei, flag, bofs, tmp);
    k_bcsr<<<NBUCK, 256, 0, stream>>>(tmp, bbase, rowptr, dinv, csrsrc);

    const int G = (N_NODES + 63) / 64;          // 1563 node groups
    const int gemm_blocks = (G * 2 + 3) / 4;    // 782

    // layer 1: gemm -> bufA; fused agg1+gemm64: gather bufA -> bufB
    k_gemm_in_ws<<<gemm_blocks, 256, 0, stream>>>(x, Wf + WF_W1, dinv, bufA, flag);
    k_aggemm<<<N_NODES / 16, 256, 0, stream>>>(bufA, rowptr, csrsrc, dinv,
                                               Wf + WF_B1, Wf + WF_W2, bufB);

    // layer 2 aggregate: gather bufB -> bufA (relu'd h rows)
    k_agg<<<(N_NODES + 15) / 16, 256, 0, stream>>>(bufB, rowptr, csrsrc, dinv, Wf + WF_B2, bufA);

    // edge MLP projections: read bufA; P1 -> bufB, P2 in place on bufA (barrier-protected)
    k_pair_ws<<<G, 256, 0, stream>>>(bufA, Wf + WF_L1W, bufB);
    // 8 lanes per edge-quad -> 2 threads/edge -> 3.2M threads
    k_edge<<<(N_EDGES * 2 + 255) / 256, 256, 0, stream>>>(ei, bufB, bufA, Wf, flag, d_out);
}

// Round 13
// 350.834 us; speedup vs baseline: 1.0406x; 1.0406x over previous
//
#include <hip/hip_runtime.h>
#include <hip/hip_bf16.h>

#define N_NODES 100000
#define N_EDGES 1600000
#define F_IN 128
#define HID 64
#define SCAN_NB 98   // ceil(100000/1024) — grid for detect
#define NBUCK 391    // ceil(100000/256) column buckets
#define BSH 8        // 256 nodes per bucket
#define NSCB 784     // blocks for count/scatter passes (~3 blocks/CU)

typedef __attribute__((ext_vector_type(8))) short short8;
typedef __attribute__((ext_vector_type(2))) float vf2;

__device__ __forceinline__ float bfbits2f(unsigned short u) {
    union { unsigned int i; float f; } v;
    v.i = ((unsigned int)u) << 16;
    return v.f;
}
__device__ __forceinline__ unsigned short f2bfbits(float f) {
    union { float f; unsigned int i; } v;
    v.f = f;
    unsigned int r = v.i + 0x7FFFu + ((v.i >> 16) & 1u);  // RNE
    return (unsigned short)(r >> 16);
}
__device__ __forceinline__ unsigned int pack2bf(float a, float b) {
    return ((unsigned int)f2bfbits(b) << 16) | (unsigned int)f2bfbits(a);
}
__device__ __forceinline__ float lo_bf(unsigned int w) { return bfbits2f((unsigned short)(w & 0xFFFF)); }
__device__ __forceinline__ float hi_bf(unsigned int w) { return bfbits2f((unsigned short)(w >> 16)); }
// unpack u32 (2 packed bf16) -> float2: {lo<<16, hi&mask} reinterpreted. 2 VALU ops for 2 channels.
__device__ __forceinline__ vf2 unpack_bf2(unsigned int w) {
    union { unsigned int i[2]; vf2 f; } u;
    u.i[0] = w << 16;
    u.i[1] = w & 0xFFFF0000u;
    return u.f;
}

// ---- detect flags AND zero bucket counters; block 0 does flag logic ----
__global__ void k_detect(const int* __restrict__ ei, const unsigned int* __restrict__ x32,
                         int* __restrict__ flag, int* __restrict__ gcount) {
    int gid = blockIdx.x * 1024 + threadIdx.x;
    if (gid < NBUCK) gcount[gid] = 0;
    if (blockIdx.x != 0) return;
    __shared__ int s_odd, s_cnt;
    if (threadIdx.x == 0) { s_odd = 0; s_cnt = 0; }
    __syncthreads();
    int t = threadIdx.x;  // 1024 threads
    if (ei[2 * t + 1] != 0) atomicOr(&s_odd, 1);
    if (t < 256) {
        unsigned int u = x32[t];
        unsigned int e = (u >> 7) & 0xFF;
        if (e >= 0x68 && e <= 0x97) atomicAdd(&s_cnt, 1);
    }
    __syncthreads();
    if (t == 0) {
        flag[0] = (s_odd == 0) ? 1 : 0;
        flag[1] = (s_cnt >= 160) ? 1 : 0;
    }
}

__device__ __forceinline__ int clampN(int v) {
    v = v < 0 ? 0 : v;
    return v > (N_NODES - 1) ? (N_NODES - 1) : v;
}
__device__ __forceinline__ int load_row(const int* __restrict__ ei, int f, int e) {
    return clampN(f ? ei[2 * e] : ei[e]);
}
__device__ __forceinline__ int load_col(const int* __restrict__ ei, int f, int e) {
    return clampN(f ? ei[2 * (N_EDGES + e)] : ei[N_EDGES + e]);
}

// ---- fp32 weight scratch layout (floats) ----
#define WF_W1   0
#define WF_W2   8192
#define WF_L1W  12288
#define WF_B1   20480
#define WF_B2   20544
#define WF_L1B  20608
#define WF_L2W  20672
#define WF_L2B  20800
#define WF_TOT  20802

__global__ void k_prep(const void* W1, const void* W2, const void* L1W,
                       const void* b1, const void* b2, const void* L1b,
                       const void* L2W, const void* L2b,
                       const int* __restrict__ flag, float* __restrict__ Wf) {
    int idx = blockIdx.x * blockDim.x + threadIdx.x;
    if (idx >= WF_TOT) return;
    int bf = flag[1];
    const void* src; int k;
    if      (idx < WF_W2)  { src = W1;  k = idx; }
    else if (idx < WF_L1W) { src = W2;  k = idx - WF_W2; }
    else if (idx < WF_B1)  { src = L1W; k = idx - WF_L1W; }
    else if (idx < WF_B2)  { src = b1;  k = idx - WF_B1; }
    else if (idx < WF_L1B) { src = b2;  k = idx - WF_B2; }
    else if (idx < WF_L2W) { src = L1b; k = idx - WF_L1B; }
    else if (idx < WF_L2B) { src = L2W; k = idx - WF_L2W; }
    else                   { src = L2b; k = idx - WF_L2B; }
    Wf[idx] = bf ? bfbits2f(((const unsigned short*)src)[k]) : ((const float*)src)[k];
}

// ===== bucketed CSR build (deterministic, no global cursor atomics) =====

// ---- pass 1: LDS histogram; emit per-block hist matrix + global bucket counts ----
__global__ void __launch_bounds__(256) k_bcount(const int* __restrict__ ei,
                                                const int* __restrict__ flag,
                                                int* __restrict__ gcount,
                                                int* __restrict__ bhist) {
    __shared__ int hist[NBUCK];
    for (int t = threadIdx.x; t < NBUCK; t += 256) hist[t] = 0;
    __syncthreads();
    int f = flag[0];
    const int EPB = (N_EDGES + NSCB - 1) / NSCB;
    int base = blockIdx.x * EPB;
    int end = base + EPB; if (end > N_EDGES) end = N_EDGES;
    for (int e = base + threadIdx.x; e < end; e += 256)
        atomicAdd(&hist[load_col(ei, f, e) >> BSH], 1);
    __syncthreads();
    for (int t = threadIdx.x; t < NBUCK; t += 256) {
        int hv = hist[t];
        bhist[(size_t)blockIdx.x * NBUCK + t] = hv;   // coalesced
        if (hv) atomicAdd(&gcount[t], hv);
    }
}

// ---- pass 2 (fused): block b scans the 391 bucket totals itself (writes bbase[b]),
// then scans its bucket's per-block column (784 wide) -> bofs[b][blk]. ----
__global__ void __launch_bounds__(1024) k_bscan2(const int* __restrict__ gcount,
                                                 const int* __restrict__ bhist,
                                                 int* __restrict__ bbase,
                                                 int* __restrict__ bofs,
                                                 int* __restrict__ rowptr) {
    __shared__ int s[1024];
    __shared__ int bb;
    int b = blockIdx.x;
    int t = threadIdx.x;
    // scan bucket totals -> this bucket's global base
    int v = (t < NBUCK) ? gcount[t] : 0;
    s[t] = v; __syncthreads();
    for (int off = 1; off < 1024; off <<= 1) {
        int add = (t >= off) ? s[t - off] : 0;
        __syncthreads();
        s[t] += add;
        __syncthreads();
    }
    if (t == b) { bb = s[t] - v; bbase[b] = bb; }
    if (b == 0 && t == 0) { bbase[NBUCK] = N_EDGES; rowptr[N_NODES] = N_EDGES; }
    __syncthreads();
    int base_b = bb;
    // per-(block,bucket) exact bases for bucket b
    int v2 = (t < NSCB) ? bhist[(size_t)t * NBUCK + b] : 0;
    s[t] = v2; __syncthreads();
    for (int off = 1; off < 1024; off <<= 1) {
        int add = (t >= off) ? s[t - off] : 0;
        __syncthreads();
        s[t] += add;
        __syncthreads();
    }
    if (t < NSCB) bofs[(size_t)b * NSCB + t] = base_b + s[t] - v2;  // coalesced
}

// ---- pass 3: LDS bucket-sort, then MONOTONE global writes (lbase[b] ascending in b)
// EPB=2041 -> ~24 KB LDS, 512 threads, 784 blocks (~3 blocks/CU) ----
__global__ void __launch_bounds__(512) k_bscatter(const int* __restrict__ ei,
                                                  const int* __restrict__ flag,
                                                  const int* __restrict__ bofs,
                                                  unsigned int* __restrict__ tmp) {
    __shared__ unsigned int sortedv[2048];  // EPB=2041 padded
    __shared__ int sorteda[2048];
    __shared__ int lbase[NBUCK];
    __shared__ int hist[NBUCK];
    __shared__ int lofs[NBUCK];
    __shared__ int s[512];
    int t = threadIdx.x;
    for (int i = t; i < NBUCK; i += 512) {
        lbase[i] = bofs[(size_t)i * NSCB + blockIdx.x];
        hist[i] = 0;
    }
    __syncthreads();
    int f = flag[0];
    const int EPB = (N_EDGES + NSCB - 1) / NSCB;
    int base = blockIdx.x * EPB;
    int end = base + EPB; if (end > N_EDGES) end = N_EDGES;
    for (int e = base + t; e < end; e += 512)
        atomicAdd(&hist[load_col(ei, f, e) >> BSH], 1);
    __syncthreads();
    int v = (t < NBUCK) ? hist[t] : 0;
    s[t] = v; __syncthreads();
    for (int off = 1; off < 512; off <<= 1) {
        int add = (t >= off) ? s[t - off] : 0;
        __syncthreads();
        s[t] += add;
        __syncthreads();
    }
    if (t < NBUCK) { lofs[t] = s[t] - v; hist[t] = 0; }  // hist becomes rank cursor
    __syncthreads();
    for (int e = base + t; e < end; e += 512) {           // ei re-read is L2-warm
        int r = load_row(ei, f, e), c = load_col(ei, f, e);
        int b = c >> BSH;
        int rk = atomicAdd(&hist[b], 1);
        int sp = lofs[b] + rk;
        sortedv[sp] = ((unsigned int)r << BSH) | (unsigned int)(c & 255);
        sorteda[sp] = lbase[b] + rk;
    }
    __syncthreads();
    int cnt = end - base;
    for (int i = t; i < cnt; i += 512)
        tmp[sorteda[i]] = sortedv[i];
}

// ---- pass 4: per-bucket sub-CSR entirely in LDS (emits csr_src, rowptr, dinv).
// 256 nodes/bucket, one node per thread. ----
__global__ void __launch_bounds__(256) k_bcsr(const unsigned int* __restrict__ tmp,
                                              const int* __restrict__ bbase,
                                              int* __restrict__ rowptr,
                                              float* __restrict__ dinv,
                                              int* __restrict__ csr_src) {
    __shared__ int nh[256];    // per-node counts (stable after count phase)
    __shared__ int nrp[256];   // inclusive prefix
    __shared__ int ncur[256];  // placement cursor
    int nb = blockIdx.x;
    int s0 = bbase[nb], s1 = bbase[nb + 1];
    int cnt = s1 - s0;
    int t = threadIdx.x;
    nh[t] = 0; ncur[t] = 0;
    __syncthreads();
    for (int i = t; i < cnt; i += 256)
        atomicAdd(&nh[tmp[s0 + i] & 255], 1);
    __syncthreads();
    nrp[t] = nh[t];
    __syncthreads();
    for (int off = 1; off < 256; off <<= 1) {
        int add = (t >= off) ? nrp[t - off] : 0;
        __syncthreads();
        nrp[t] += add;
        __syncthreads();
    }
    int nodeBase = nb * 256;
    if (nodeBase + t < N_NODES) {
        rowptr[nodeBase + t] = s0 + nrp[t] - nh[t];  // exclusive prefix
        dinv[nodeBase + t] = rsqrtf((float)(nh[t] + 1));
    }
    __syncthreads();
    for (int i = t; i < cnt; i += 256) {
        unsigned int v = tmp[s0 + i];
        int cl = v & 255;
        int rk = atomicAdd(&ncur[cl], 1);
        csr_src[s0 + (nrp[cl] - nh[cl]) + rk] = (int)(v >> BSH);
    }
}

// ===== node tables: packed bf16 rows, 32 u32 (=64 ch) per node =====
// packed-f32 inner loop: acc as vf2[16], weight rows as vf2 pairs, scalar x
// broadcast -> v_pk_fma_f32 halves VALU issue count
__device__ __forceinline__ void fma8_32p(const float* xv, const float* __restrict__ W,
                                         int k0, int coloff, vf2* acc) {
#pragma unroll
    for (int t = 0; t < 8; t++) {
        const vf2* wr = (const vf2*)(W + (k0 + t) * 64 + coloff);
        vf2 xb = {xv[t], xv[t]};
#pragma unroll
        for (int j = 0; j < 16; j++) acc[j] += xb * wr[j];
    }
}

// ---- layer-1 GEMM (wave-split): x [N,128] @ Wf[128,64] -> hs bf16; scale=dinv ----
__global__ void __launch_bounds__(256) k_gemm_in_ws(const void* __restrict__ x,
                                                    const float* __restrict__ Wf,
                                                    const float* __restrict__ dinv,
                                                    unsigned int* __restrict__ hs,
                                                    const int* __restrict__ flag) {
    int wv = __builtin_amdgcn_readfirstlane(threadIdx.x >> 6);  // 0..3, scalar
    int wid = blockIdx.x * 4 + wv;
    int group = wid >> 1;
    int half = wid & 1;          // scalar: col-half
    int lane = threadIdx.x & 63;
    int node = group * 64 + lane;
    if (node >= N_NODES) return;
    int bf = flag[1];
    int coloff = half * 32;
    vf2 acc[16];
#pragma unroll
    for (int j = 0; j < 16; j++) acc[j] = (vf2){0.f, 0.f};
    if (bf) {
        const unsigned short* xp = (const unsigned short*)x + (size_t)node * F_IN;
#pragma unroll 2
        for (int k0 = 0; k0 < F_IN; k0 += 8) {
            short8 raw = *(const short8*)(xp + k0);
            float xv[8];
#pragma unroll
            for (int t = 0; t < 8; t++) xv[t] = bfbits2f((unsigned short)raw[t]);
            fma8_32p(xv, Wf, k0, coloff, acc);
        }
    } else {
        const float* xp = (const float*)x + (size_t)node * F_IN;
#pragma unroll 2
        for (int k0 = 0; k0 < F_IN; k0 += 8) {
            float4 a = *(const float4*)(xp + k0);
            float4 b = *(const float4*)(xp + k0 + 4);
            float xv[8] = {a.x, a.y, a.z, a.w, b.x, b.y, b.z, b.w};
            fma8_32p(xv, Wf, k0, coloff, acc);
        }
    }
    float s = dinv[node];
    unsigned int* op = hs + (size_t)node * 32 + half * 16;
#pragma unroll
    for (int j = 0; j < 16; j++) op[j] = pack2bf(acc[j].x * s, acc[j].y * s);
}

// ---- layer-2 GEMM (wave-split): in bf16 [N,64] @ W[64][64] -> out bf16; scale=dinv ----
__global__ void __launch_bounds__(256) k_gemm64_ws(const unsigned int* __restrict__ in,
                                                   const float* __restrict__ W,
                                                   const float* __restrict__ dinv,
                                                   unsigned int* __restrict__ out) {
    int wv = __builtin_amdgcn_readfirstlane(threadIdx.x >> 6);
    int wid = blockIdx.x * 4 + wv;
    int group = wid >> 1;
    int half = wid & 1;
    int lane = threadIdx.x & 63;
    int node = group * 64 + lane;
    if (node >= N_NODES) return;
    int coloff = half * 32;
    vf2 acc[16];
#pragma unroll
    for (int j = 0; j < 16; j++) acc[j] = (vf2){0.f, 0.f};
    const unsigned short* hp = (const unsigned short*)(in + (size_t)node * 32);
#pragma unroll 2
    for (int k0 = 0; k0 < 64; k0 += 8) {
        short8 raw = *(const short8*)(hp + k0);
        float xv[8];
#pragma unroll
        for (int t = 0; t < 8; t++) xv[t] = bfbits2f((unsigned short)raw[t]);
        fma8_32p(xv, W, k0, coloff, acc);
    }
    float s = dinv[node];
    unsigned int* op = out + (size_t)node * 32 + half * 16;
#pragma unroll
    for (int j = 0; j < 16; j++) op[j] = pack2bf(acc[j].x * s, acc[j].y * s);
}

// ---- edge-MLP projections (wave-split, 4 tasks): block = 64 nodes x 4 waves ----
__global__ void __launch_bounds__(256) k_pair_ws(unsigned int* __restrict__ h,
                                                 const float* __restrict__ W,  // L1W [128][64]
                                                 unsigned int* __restrict__ P1) {
    int task = __builtin_amdgcn_readfirstlane(threadIdx.x >> 6);  // 0..3, scalar
    int lane = threadIdx.x & 63;
    int node = blockIdx.x * 64 + lane;
    bool valid = node < N_NODES;
    int coloff = (task & 1) * 32;
    const float* Wb = W + (task >> 1) * 64 * 64;  // k-row base: P1 rows 0.., P2 rows 64..
    vf2 acc[16];
#pragma unroll
    for (int j = 0; j < 16; j++) acc[j] = (vf2){0.f, 0.f};
    if (valid) {
        const unsigned short* hp = (const unsigned short*)(h + (size_t)node * 32);
#pragma unroll 2
        for (int k0 = 0; k0 < 64; k0 += 8) {
            short8 raw = *(const short8*)(hp + k0);
            float xv[8];
#pragma unroll
            for (int t = 0; t < 8; t++) xv[t] = bfbits2f((unsigned short)raw[t]);
            fma8_32p(xv, Wb, k0, coloff, acc);
        }
    }
    __syncthreads();  // all reads of this block's 64 h-rows complete before P2 writes
    if (valid) {
        unsigned int* op = (task < 2 ? P1 : h) + (size_t)node * 32 + coloff / 2;
#pragma unroll
        for (int j = 0; j < 16; j++) op[j] = pack2bf(acc[j].x, acc[j].y);
    }
}

// ---- aggregate: wave = 4 nodes; 16 lanes/node; uint2 gathers; x8 unroll
// (32 random lines in flight per wave — measured optimum) ----
__global__ void __launch_bounds__(256) k_agg(const unsigned int* __restrict__ hs,
                                             const int* __restrict__ rowptr,
                                             const int* __restrict__ csr_src,
                                             const float* __restrict__ dinv,
                                             const float* __restrict__ bias,
                                             unsigned int* __restrict__ h) {
    int wid = blockIdx.x * 4 + (threadIdx.x >> 6);
    int lane = threadIdx.x & 63;
    int q = lane >> 4;          // node within wave (0..3)
    int w = lane & 15;          // uint2 index within row: channels 4w..4w+3
    int node = wid * 4 + q;
    if (node >= N_NODES) return;
    const uint2* hp = (const uint2*)hs;  // row = 16 uint2
    uint2 sw = hp[(size_t)node * 16 + w];
    vf2 aA = unpack_bf2(sw.x), aB = unpack_bf2(sw.y);
    int k = rowptr[node], k1 = rowptr[node + 1];
    for (; k + 7 < k1; k += 8) {
        int s0 = csr_src[k],     s1 = csr_src[k + 1], s2 = csr_src[k + 2], s3 = csr_src[k + 3];
        int s4 = csr_src[k + 4], s5 = csr_src[k + 5], s6 = csr_src[k + 6], s7 = csr_src[k + 7];
        uint2 w0 = hp[(size_t)s0 * 16 + w];
        uint2 w1 = hp[(size_t)s1 * 16 + w];
        uint2 w2 = hp[(size_t)s2 * 16 + w];
        uint2 w3 = hp[(size_t)s3 * 16 + w];
        uint2 w4 = hp[(size_t)s4 * 16 + w];
        uint2 w5 = hp[(size_t)s5 * 16 + w];
        uint2 w6 = hp[(size_t)s6 * 16 + w];
        uint2 w7 = hp[(size_t)s7 * 16 + w];
        aA += ((unpack_bf2(w0.x) + unpack_bf2(w1.x)) + (unpack_bf2(w2.x) + unpack_bf2(w3.x)))
            + ((unpack_bf2(w4.x) + unpack_bf2(w5.x)) + (unpack_bf2(w6.x) + unpack_bf2(w7.x)));
        aB += ((unpack_bf2(w0.y) + unpack_bf2(w1.y)) + (unpack_bf2(w2.y) + unpack_bf2(w3.y)))
            + ((unpack_bf2(w4.y) + unpack_bf2(w5.y)) + (unpack_bf2(w6.y) + unpack_bf2(w7.y)));
    }
    for (; k + 3 < k1; k += 4) {
        int s0 = csr_src[k], s1 = csr_src[k + 1], s2 = csr_src[k + 2], s3 = csr_src[k + 3];
        uint2 w0 = hp[(size_t)s0 * 16 + w];
        uint2 w1 = hp[(size_t)s1 * 16 + w];
        uint2 w2 = hp[(size_t)s2 * 16 + w];
        uint2 w3 = hp[(size_t)s3 * 16 + w];
        aA += (unpack_bf2(w0.x) + unpack_bf2(w1.x)) + (unpack_bf2(w2.x) + unpack_bf2(w3.x));
        aB += (unpack_bf2(w0.y) + unpack_bf2(w1.y)) + (unpack_bf2(w2.y) + unpack_bf2(w3.y));
    }
    for (; k < k1; k++) {
        uint2 w0 = hp[(size_t)csr_src[k] * 16 + w];
        aA += unpack_bf2(w0.x);
        aB += unpack_bf2(w0.y);
    }
    float di = dinv[node];
    vf2 b0 = *(const vf2*)(bias + 4 * w);
    vf2 b1 = *(const vf2*)(bias + 4 * w + 2);
    float v0 = fmaxf(fmaf(aA.x, di, b0.x), 0.f);
    float v1 = fmaxf(fmaf(aA.y, di, b0.y), 0.f);
    float v2 = fmaxf(fmaf(aB.x, di, b1.x), 0.f);
    float v3 = fmaxf(fmaf(aB.y, di, b1.y), 0.f);
    uint2 ow; ow.x = pack2bf(v0, v1); ow.y = pack2bf(v2, v3);
    *(uint2*)(h + (size_t)node * 32 + 2 * w) = ow;
}

// ---- edge MLP: 8 lanes per edge-quad, direct per-lane index loads, packed-f32
// channel math (measured: 53.0 µs, VGPR 36, occupancy 61%) ----
__global__ void __launch_bounds__(256) k_edge(const int* __restrict__ ei,
                       const unsigned int* __restrict__ P1, const unsigned int* __restrict__ P2,
                       const float* __restrict__ Wf, const int* __restrict__ flag,
                       void* __restrict__ out) {
    int tid = blockIdx.x * 256 + threadIdx.x;
    int g = tid >> 3;       // quad index: edges 4g .. 4g+3
    int k = tid & 7;        // sub-lane: channels j = 8k .. 8k+7
    int e0 = g * 4;
    if (e0 >= N_EDGES) return;  // N_EDGES % 4 == 0 -> e0..e0+3 all valid
    int f = flag[0];
    int r0 = load_row(ei, f, e0),     c0 = load_col(ei, f, e0);
    int r1 = load_row(ei, f, e0 + 1), c1 = load_col(ei, f, e0 + 1);
    int r2 = load_row(ei, f, e0 + 2), c2 = load_col(ei, f, e0 + 2);
    int r3 = load_row(ei, f, e0 + 3), c3 = load_col(ei, f, e0 + 3);
    // issue all 8 gathers before any compute
    uint4 ua0 = *(const uint4*)(P1 + (size_t)r0 * 32 + k * 4);
    uint4 ub0 = *(const uint4*)(P2 + (size_t)c0 * 32 + k * 4);
    uint4 ua1 = *(const uint4*)(P1 + (size_t)r1 * 32 + k * 4);
    uint4 ub1 = *(const uint4*)(P2 + (size_t)c1 * 32 + k * 4);
    uint4 ua2 = *(const uint4*)(P1 + (size_t)r2 * 32 + k * 4);
    uint4 ub2 = *(const uint4*)(P2 + (size_t)c2 * 32 + k * 4);
    uint4 ua3 = *(const uint4*)(P1 + (size_t)r3 * 32 + k * 4);
    uint4 ub3 = *(const uint4*)(P2 + (size_t)c3 * 32 + k * 4);
    // bias pairs and L2-weight pairs for this lane's 8 channels
    vf2 b2[4], wp[8];
#pragma unroll
    for (int t = 0; t < 4; t++) b2[t] = *(const vf2*)(Wf + WF_L1B + k * 8 + 2 * t);
#pragma unroll
    for (int t = 0; t < 8; t++) wp[t] = *(const vf2*)(Wf + WF_L2W + k * 16 + 2 * t);
    vf2 acc[4] = {{0.f, 0.f}, {0.f, 0.f}, {0.f, 0.f}, {0.f, 0.f}};
    auto edge_mlp = [&](const uint4& ua, const uint4& ub, int i) {
        unsigned int wa[4] = {ua.x, ua.y, ua.z, ua.w};
        unsigned int wb[4] = {ub.x, ub.y, ub.z, ub.w};
#pragma unroll
        for (int t = 0; t < 4; t++) {
            vf2 z = unpack_bf2(wa[t]) + unpack_bf2(wb[t]) + b2[t];
            z = __builtin_elementwise_max(z, (vf2){0.f, 0.f});
            acc[i] += z.x * wp[2 * t];      // (s0,s1) += z_ch0 * (w00,w01)
            acc[i] += z.y * wp[2 * t + 1];  // (s0,s1) += z_ch1 * (w10,w11)
        }
    };
    edge_mlp(ua0, ub0, 0);
    edge_mlp(ua1, ub1, 1);
    edge_mlp(ua2, ub2, 2);
    edge_mlp(ua3, ub3, 3);
    float s0[4], s1[4];
#pragma unroll
    for (int i = 0; i < 4; i++) { s0[i] = acc[i].x; s1[i] = acc[i].y; }
#pragma unroll
    for (int off = 1; off < 8; off <<= 1) {
#pragma unroll
        for (int i = 0; i < 4; i++) {
            s0[i] += __shfl_xor(s0[i], off);
            s1[i] += __shfl_xor(s1[i], off);
        }
    }
    if (k == 0) {
        float b0f = Wf[WF_L2B + 0], b1f = Wf[WF_L2B + 1];
        float z0[4], z1[4];
#pragma unroll
        for (int i = 0; i < 4; i++) {
            float za = s0[i] + b0f, zb = s1[i] + b1f;
            float m = fmaxf(za, zb);
            float lse = m + __logf(__expf(za - m) + __expf(zb - m));
            z0[i] = za - lse; z1[i] = zb - lse;
        }
        if (flag[1]) {
            uint4 v;
            v.x = pack2bf(z0[0], z1[0]); v.y = pack2bf(z0[1], z1[1]);
            v.z = pack2bf(z0[2], z1[2]); v.w = pack2bf(z0[3], z1[3]);
            *(uint4*)((unsigned int*)out + e0) = v;
        } else {
            float4 v01, v23;
            v01.x = z0[0]; v01.y = z1[0]; v01.z = z0[1]; v01.w = z1[1];
            v23.x = z0[2]; v23.y = z1[2]; v23.z = z0[3]; v23.w = z1[3];
            float4* op = (float4*)((float2*)out + e0);
            op[0] = v01;
            op[1] = v23;
        }
    }
}

extern "C" void kernel_launch(void* const* d_in, const int* in_sizes, int n_in,
                              void* d_out, int out_size, void* d_ws, size_t ws_size,
                              hipStream_t stream) {
    const void* x   = d_in[0];
    const int*  ei  = (const int*)d_in[1];

    char* ws = (char*)d_ws;
    constexpr size_t KB = 1024;

    int*   gcount = (int*)(ws);                    // 391 ints
    int*   bbase  = (int*)(ws + 8 * KB);           // 392 ints
    int*   flag   = (int*)(ws + 12 * KB);          // 8 B
    float* Wf     = (float*)(ws + 16 * KB);        // 83.2 KB -> ends ~99 KB
    float* dinv   = (float*)(ws + 400 * KB);       // 400 KB
    int*   rowptr = (int*)(ws + 800 * KB);         // 400 KB + 4
    unsigned int* tmp = (unsigned int*)(ws + 1300 * KB);  // 6400 KB -> ends 7700
    int*   csrsrc = (int*)(ws + 7700 * KB);        // 6400 KB -> ends 14100
    int*   bhist  = (int*)(ws + 14100 * KB);       // 784*391*4 = 1.23 MB -> ends ~15330
    int*   bofs   = (int*)(ws + 15400 * KB);       // 1.23 MB -> ends ~16630
    unsigned int* hs = (unsigned int*)(ws + 20500 * KB);  // 12800 KB (later P1)
    unsigned int* h  = (unsigned int*)(ws + 33300 * KB);  // 12800 KB (later P2)

    // detect + bucket-counter zero fused
    k_detect<<<SCAN_NB, 1024, 0, stream>>>(ei, (const unsigned int*)x, flag, gcount);
    k_prep<<<(WF_TOT + 255) / 256, 256, 0, stream>>>(d_in[2], d_in[4], d_in[6], d_in[3],
                                                     d_in[5], d_in[7], d_in[8], d_in[9],
                                                     flag, Wf);

    // bucketed CSR build: count -> fused scans -> LDS-sorted scatter -> sub-CSR
    k_bcount<<<NSCB, 256, 0, stream>>>(ei, flag, gcount, bhist);
    k_bscan2<<<NBUCK, 1024, 0, stream>>>(gcount, bhist, bbase, bofs, rowptr);
    k_bscatter<<<NSCB, 512, 0, stream>>>(ei, flag, bofs, tmp);
    k_bcsr<<<NBUCK, 256, 0, stream>>>(tmp, bbase, rowptr, dinv, csrsrc);

    const int G = (N_NODES + 63) / 64;          // 1563 node groups
    const int gemm_blocks = (G * 2 + 3) / 4;    // 782

    // layer 1
    k_gemm_in_ws<<<gemm_blocks, 256, 0, stream>>>(x, Wf + WF_W1, dinv, hs, flag);
    k_agg<<<(N_NODES + 15) / 16, 256, 0, stream>>>(hs, rowptr, csrsrc, dinv, Wf + WF_B1, h);

    // layer 2
    k_gemm64_ws<<<gemm_blocks, 256, 0, stream>>>(h, Wf + WF_W2, dinv, hs);
    k_agg<<<(N_NODES + 15) / 16, 256, 0, stream>>>(hs, rowptr, csrsrc, dinv, Wf + WF_B2, h);

    // edge MLP: P1 -> hs, P2 in place on h (barrier-protected); original-order edge pass
    k_pair_ws<<<G, 256, 0, stream>>>(h, Wf + WF_L1W, hs);
    // 8 lanes per edge-quad -> 2 threads/edge -> 3.2M threads
    k_edge<<<(N_EDGES * 2 + 255) / 256, 256, 0, stream>>>(ei, hs, h, Wf, flag, d_out);
}

// Round 14
// 341.222 us; speedup vs baseline: 1.0699x; 1.0282x over previous
//
#include <hip/hip_runtime.h>
#include <hip/hip_bf16.h>

#define N_NODES 100000
#define N_EDGES 1600000
#define F_IN 128
#define HID 64
#define SCAN_NB 98   // ceil(100000/1024) — grid for detect
#define NBUCK 391    // ceil(100000/256) column buckets
#define BSH 8        // 256 nodes per bucket
#define NSCB 392     // blocks for count/scatter passes (measured optimum; 784 regressed)

typedef __attribute__((ext_vector_type(8))) short short8;
typedef __attribute__((ext_vector_type(2))) float vf2;

__device__ __forceinline__ float bfbits2f(unsigned short u) {
    union { unsigned int i; float f; } v;
    v.i = ((unsigned int)u) << 16;
    return v.f;
}
__device__ __forceinline__ unsigned short f2bfbits(float f) {
    union { float f; unsigned int i; } v;
    v.f = f;
    unsigned int r = v.i + 0x7FFFu + ((v.i >> 16) & 1u);  // RNE
    return (unsigned short)(r >> 16);
}
__device__ __forceinline__ unsigned int pack2bf(float a, float b) {
    return ((unsigned int)f2bfbits(b) << 16) | (unsigned int)f2bfbits(a);
}
__device__ __forceinline__ float lo_bf(unsigned int w) { return bfbits2f((unsigned short)(w & 0xFFFF)); }
__device__ __forceinline__ float hi_bf(unsigned int w) { return bfbits2f((unsigned short)(w >> 16)); }
// unpack u32 (2 packed bf16) -> float2: {lo<<16, hi&mask} reinterpreted. 2 VALU ops for 2 channels.
__device__ __forceinline__ vf2 unpack_bf2(unsigned int w) {
    union { unsigned int i[2]; vf2 f; } u;
    u.i[0] = w << 16;
    u.i[1] = w & 0xFFFF0000u;
    return u.f;
}

// ---- detect flags AND zero bucket counters; block 0 does flag logic ----
__global__ void k_detect(const int* __restrict__ ei, const unsigned int* __restrict__ x32,
                         int* __restrict__ flag, int* __restrict__ gcount) {
    int gid = blockIdx.x * 1024 + threadIdx.x;
    if (gid < NBUCK) gcount[gid] = 0;
    if (blockIdx.x != 0) return;
    __shared__ int s_odd, s_cnt;
    if (threadIdx.x == 0) { s_odd = 0; s_cnt = 0; }
    __syncthreads();
    int t = threadIdx.x;  // 1024 threads
    if (ei[2 * t + 1] != 0) atomicOr(&s_odd, 1);
    if (t < 256) {
        unsigned int u = x32[t];
        unsigned int e = (u >> 7) & 0xFF;
        if (e >= 0x68 && e <= 0x97) atomicAdd(&s_cnt, 1);
    }
    __syncthreads();
    if (t == 0) {
        flag[0] = (s_odd == 0) ? 1 : 0;
        flag[1] = (s_cnt >= 160) ? 1 : 0;
    }
}

__device__ __forceinline__ int clampN(int v) {
    v = v < 0 ? 0 : v;
    return v > (N_NODES - 1) ? (N_NODES - 1) : v;
}
__device__ __forceinline__ int load_row(const int* __restrict__ ei, int f, int e) {
    return clampN(f ? ei[2 * e] : ei[e]);
}
__device__ __forceinline__ int load_col(const int* __restrict__ ei, int f, int e) {
    return clampN(f ? ei[2 * (N_EDGES + e)] : ei[N_EDGES + e]);
}

// ---- fp32 weight scratch layout (floats) ----
#define WF_W1   0
#define WF_W2   8192
#define WF_L1W  12288
#define WF_B1   20480
#define WF_B2   20544
#define WF_L1B  20608
#define WF_L2W  20672
#define WF_L2B  20800
#define WF_TOT  20802

__global__ void k_prep(const void* W1, const void* W2, const void* L1W,
                       const void* b1, const void* b2, const void* L1b,
                       const void* L2W, const void* L2b,
                       const int* __restrict__ flag, float* __restrict__ Wf) {
    int idx = blockIdx.x * blockDim.x + threadIdx.x;
    if (idx >= WF_TOT) return;
    int bf = flag[1];
    const void* src; int k;
    if      (idx < WF_W2)  { src = W1;  k = idx; }
    else if (idx < WF_L1W) { src = W2;  k = idx - WF_W2; }
    else if (idx < WF_B1)  { src = L1W; k = idx - WF_L1W; }
    else if (idx < WF_B2)  { src = b1;  k = idx - WF_B1; }
    else if (idx < WF_L1B) { src = b2;  k = idx - WF_B2; }
    else if (idx < WF_L2W) { src = L1b; k = idx - WF_L1B; }
    else if (idx < WF_L2B) { src = L2W; k = idx - WF_L2W; }
    else                   { src = L2b; k = idx - WF_L2B; }
    Wf[idx] = bf ? bfbits2f(((const unsigned short*)src)[k]) : ((const float*)src)[k];
}

// ===== bucketed CSR build (deterministic, no global cursor atomics) =====

// ---- pass 1: LDS histogram; emit per-block hist matrix + global bucket counts ----
__global__ void __launch_bounds__(256) k_bcount(const int* __restrict__ ei,
                                                const int* __restrict__ flag,
                                                int* __restrict__ gcount,
                                                int* __restrict__ bhist) {
    __shared__ int hist[NBUCK];
    for (int t = threadIdx.x; t < NBUCK; t += 256) hist[t] = 0;
    __syncthreads();
    int f = flag[0];
    const int EPB = (N_EDGES + NSCB - 1) / NSCB;
    int base = blockIdx.x * EPB;
    int end = base + EPB; if (end > N_EDGES) end = N_EDGES;
    for (int e = base + threadIdx.x; e < end; e += 256)
        atomicAdd(&hist[load_col(ei, f, e) >> BSH], 1);
    __syncthreads();
    for (int t = threadIdx.x; t < NBUCK; t += 256) {
        int hv = hist[t];
        bhist[(size_t)blockIdx.x * NBUCK + t] = hv;   // coalesced
        if (hv) atomicAdd(&gcount[t], hv);
    }
}

// ---- pass 2 (fused): block b scans the 391 bucket totals itself (writes bbase[b]),
// then scans its bucket's per-block column -> bofs[b][blk]. ----
__global__ void __launch_bounds__(512) k_bscan2(const int* __restrict__ gcount,
                                                const int* __restrict__ bhist,
                                                int* __restrict__ bbase,
                                                int* __restrict__ bofs,
                                                int* __restrict__ rowptr) {
    __shared__ int s[512];
    __shared__ int bb;
    int b = blockIdx.x;
    int t = threadIdx.x;
    // scan bucket totals -> this bucket's global base
    int v = (t < NBUCK) ? gcount[t] : 0;
    s[t] = v; __syncthreads();
    for (int off = 1; off < 512; off <<= 1) {
        int add = (t >= off) ? s[t - off] : 0;
        __syncthreads();
        s[t] += add;
        __syncthreads();
    }
    if (t == b) { bb = s[t] - v; bbase[b] = bb; }
    if (b == 0 && t == 0) { bbase[NBUCK] = N_EDGES; rowptr[N_NODES] = N_EDGES; }
    __syncthreads();
    int base_b = bb;
    // per-(block,bucket) exact bases for bucket b
    int v2 = (t < NSCB) ? bhist[(size_t)t * NBUCK + b] : 0;
    s[t] = v2; __syncthreads();
    for (int off = 1; off < 512; off <<= 1) {
        int add = (t >= off) ? s[t - off] : 0;
        __syncthreads();
        s[t] += add;
        __syncthreads();
    }
    if (t < NSCB) bofs[(size_t)b * NSCB + t] = base_b + s[t] - v2;  // coalesced
}

// ---- pass 3: LDS bucket-sort, then MONOTONE global writes (lbase[b] ascending in b
// -> the sorted sweep's addresses strictly increase) ----
__global__ void __launch_bounds__(512) k_bscatter(const int* __restrict__ ei,
                                                  const int* __restrict__ flag,
                                                  const int* __restrict__ bofs,
                                                  unsigned int* __restrict__ tmp) {
    __shared__ unsigned int sortedv[4096];  // EPB=4082 padded
    __shared__ int sorteda[4096];
    __shared__ int lbase[NBUCK];
    __shared__ int hist[NBUCK];
    __shared__ int lofs[NBUCK];
    __shared__ int s[512];
    int t = threadIdx.x;
    for (int i = t; i < NBUCK; i += 512) {
        lbase[i] = bofs[(size_t)i * NSCB + blockIdx.x];
        hist[i] = 0;
    }
    __syncthreads();
    int f = flag[0];
    const int EPB = (N_EDGES + NSCB - 1) / NSCB;
    int base = blockIdx.x * EPB;
    int end = base + EPB; if (end > N_EDGES) end = N_EDGES;
    for (int e = base + t; e < end; e += 512)
        atomicAdd(&hist[load_col(ei, f, e) >> BSH], 1);
    __syncthreads();
    int v = (t < NBUCK) ? hist[t] : 0;
    s[t] = v; __syncthreads();
    for (int off = 1; off < 512; off <<= 1) {
        int add = (t >= off) ? s[t - off] : 0;
        __syncthreads();
        s[t] += add;
        __syncthreads();
    }
    if (t < NBUCK) { lofs[t] = s[t] - v; hist[t] = 0; }  // hist becomes rank cursor
    __syncthreads();
    for (int e = base + t; e < end; e += 512) {           // ei re-read is L2-warm
        int r = load_row(ei, f, e), c = load_col(ei, f, e);
        int b = c >> BSH;
        int rk = atomicAdd(&hist[b], 1);
        int sp = lofs[b] + rk;
        sortedv[sp] = ((unsigned int)r << BSH) | (unsigned int)(c & 255);
        sorteda[sp] = lbase[b] + rk;
    }
    __syncthreads();
    int cnt = end - base;
    for (int i = t; i < cnt; i += 512)
        tmp[sorteda[i]] = sortedv[i];
}

// ---- pass 4: per-bucket sub-CSR entirely in LDS (emits csr_src, rowptr, dinv).
// 256 nodes/bucket, one node per thread. ----
__global__ void __launch_bounds__(256) k_bcsr(const unsigned int* __restrict__ tmp,
                                              const int* __restrict__ bbase,
                                              int* __restrict__ rowptr,
                                              float* __restrict__ dinv,
                                              int* __restrict__ csr_src) {
    __shared__ int nh[256];    // per-node counts (stable after count phase)
    __shared__ int nrp[256];   // inclusive prefix
    __shared__ int ncur[256];  // placement cursor
    int nb = blockIdx.x;
    int s0 = bbase[nb], s1 = bbase[nb + 1];
    int cnt = s1 - s0;
    int t = threadIdx.x;
    nh[t] = 0; ncur[t] = 0;
    __syncthreads();
    for (int i = t; i < cnt; i += 256)
        atomicAdd(&nh[tmp[s0 + i] & 255], 1);
    __syncthreads();
    nrp[t] = nh[t];
    __syncthreads();
    for (int off = 1; off < 256; off <<= 1) {
        int add = (t >= off) ? nrp[t - off] : 0;
        __syncthreads();
        nrp[t] += add;
        __syncthreads();
    }
    int nodeBase = nb * 256;
    if (nodeBase + t < N_NODES) {
        rowptr[nodeBase + t] = s0 + nrp[t] - nh[t];  // exclusive prefix
        dinv[nodeBase + t] = rsqrtf((float)(nh[t] + 1));
    }
    __syncthreads();
    for (int i = t; i < cnt; i += 256) {
        unsigned int v = tmp[s0 + i];
        int cl = v & 255;
        int rk = atomicAdd(&ncur[cl], 1);
        csr_src[s0 + (nrp[cl] - nh[cl]) + rk] = (int)(v >> BSH);
    }
}

// ===== node tables: packed bf16 rows, 32 u32 (=64 ch) per node =====
// packed-f32 inner loop: acc as vf2[16], weight rows as vf2 pairs, scalar x
// broadcast -> v_pk_fma_f32 halves VALU issue count
__device__ __forceinline__ void fma8_32p(const float* xv, const float* __restrict__ W,
                                         int k0, int coloff, vf2* acc) {
#pragma unroll
    for (int t = 0; t < 8; t++) {
        const vf2* wr = (const vf2*)(W + (k0 + t) * 64 + coloff);
        vf2 xb = {xv[t], xv[t]};
#pragma unroll
        for (int j = 0; j < 16; j++) acc[j] += xb * wr[j];
    }
}

// ---- layer-1 GEMM (wave-split): x [N,128] @ Wf[128,64] -> hs bf16; scale=dinv ----
__global__ void __launch_bounds__(256) k_gemm_in_ws(const void* __restrict__ x,
                                                    const float* __restrict__ Wf,
                                                    const float* __restrict__ dinv,
                                                    unsigned int* __restrict__ hs,
                                                    const int* __restrict__ flag) {
    int wv = __builtin_amdgcn_readfirstlane(threadIdx.x >> 6);  // 0..3, scalar
    int wid = blockIdx.x * 4 + wv;
    int group = wid >> 1;
    int half = wid & 1;          // scalar: col-half
    int lane = threadIdx.x & 63;
    int node = group * 64 + lane;
    if (node >= N_NODES) return;
    int bf = flag[1];
    int coloff = half * 32;
    vf2 acc[16];
#pragma unroll
    for (int j = 0; j < 16; j++) acc[j] = (vf2){0.f, 0.f};
    if (bf) {
        const unsigned short* xp = (const unsigned short*)x + (size_t)node * F_IN;
#pragma unroll 2
        for (int k0 = 0; k0 < F_IN; k0 += 8) {
            short8 raw = *(const short8*)(xp + k0);
            float xv[8];
#pragma unroll
            for (int t = 0; t < 8; t++) xv[t] = bfbits2f((unsigned short)raw[t]);
            fma8_32p(xv, Wf, k0, coloff, acc);
        }
    } else {
        const float* xp = (const float*)x + (size_t)node * F_IN;
#pragma unroll 2
        for (int k0 = 0; k0 < F_IN; k0 += 8) {
            float4 a = *(const float4*)(xp + k0);
            float4 b = *(const float4*)(xp + k0 + 4);
            float xv[8] = {a.x, a.y, a.z, a.w, b.x, b.y, b.z, b.w};
            fma8_32p(xv, Wf, k0, coloff, acc);
        }
    }
    float s = dinv[node];
    unsigned int* op = hs + (size_t)node * 32 + half * 16;
#pragma unroll
    for (int j = 0; j < 16; j++) op[j] = pack2bf(acc[j].x * s, acc[j].y * s);
}

// ---- layer-2 GEMM (wave-split): in bf16 [N,64] @ W[64][64] -> out bf16; scale=dinv ----
__global__ void __launch_bounds__(256) k_gemm64_ws(const unsigned int* __restrict__ in,
                                                   const float* __restrict__ W,
                                                   const float* __restrict__ dinv,
                                                   unsigned int* __restrict__ out) {
    int wv = __builtin_amdgcn_readfirstlane(threadIdx.x >> 6);
    int wid = blockIdx.x * 4 + wv;
    int group = wid >> 1;
    int half = wid & 1;
    int lane = threadIdx.x & 63;
    int node = group * 64 + lane;
    if (node >= N_NODES) return;
    int coloff = half * 32;
    vf2 acc[16];
#pragma unroll
    for (int j = 0; j < 16; j++) acc[j] = (vf2){0.f, 0.f};
    const unsigned short* hp = (const unsigned short*)(in + (size_t)node * 32);
#pragma unroll 2
    for (int k0 = 0; k0 < 64; k0 += 8) {
        short8 raw = *(const short8*)(hp + k0);
        float xv[8];
#pragma unroll
        for (int t = 0; t < 8; t++) xv[t] = bfbits2f((unsigned short)raw[t]);
        fma8_32p(xv, W, k0, coloff, acc);
    }
    float s = dinv[node];
    unsigned int* op = out + (size_t)node * 32 + half * 16;
#pragma unroll
    for (int j = 0; j < 16; j++) op[j] = pack2bf(acc[j].x * s, acc[j].y * s);
}

// ---- edge-MLP projections (wave-split, 4 tasks) with LDS row staging:
// the block's 64 h-rows are loaded ONCE (coalesced) into stride-33 LDS, then all
// 4 task-waves compute from LDS — removes the 4x redundant global row reads.
// Both phases have uniform trip counts (no degree variance), so the barrier is
// cheap — unlike the round-12 agg+gemm fusion. In-place P2 write stays safe:
// all h reads complete before the barrier. ----
__global__ void __launch_bounds__(256) k_pair_ws(unsigned int* __restrict__ h,
                                                 const float* __restrict__ W,  // L1W [128][64]
                                                 unsigned int* __restrict__ P1) {
    __shared__ unsigned int rows[64 * 33];
    int t = threadIdx.x;
    int nodeBase = blockIdx.x * 64;
#pragma unroll
    for (int i = 0; i < 8; i++) {
        int idx = t + i * 256;          // 0..2047
        int r = idx >> 5, c = idx & 31;
        int node = nodeBase + r;
        rows[r * 33 + c] = (node < N_NODES) ? h[(size_t)node * 32 + c] : 0u;
    }
    __syncthreads();
    int task = __builtin_amdgcn_readfirstlane(t >> 6);  // 0..3, scalar
    int lane = t & 63;
    int node = nodeBase + lane;
    bool valid = node < N_NODES;
    int coloff = (task & 1) * 32;
    const float* Wb = W + (task >> 1) * 64 * 64;  // k-row base: P1 rows 0.., P2 rows 64..
    vf2 acc[16];
#pragma unroll
    for (int j = 0; j < 16; j++) acc[j] = (vf2){0.f, 0.f};
    const unsigned int* hr = &rows[lane * 33];  // stride 33 -> bank (lane+c)%32, conflict-free
#pragma unroll 2
    for (int m = 0; m < 32; m += 4) {
        float xv[8];
#pragma unroll
        for (int u = 0; u < 4; u++) {
            vf2 p = unpack_bf2(hr[m + u]);
            xv[2 * u] = p.x; xv[2 * u + 1] = p.y;
        }
        fma8_32p(xv, Wb, 2 * m, coloff, acc);
    }
    if (valid) {
        unsigned int* op = (task < 2 ? P1 : h) + (size_t)node * 32 + coloff / 2;
#pragma unroll
        for (int j = 0; j < 16; j++) op[j] = pack2bf(acc[j].x, acc[j].y);
    }
}

// ---- aggregate: wave = 4 nodes; 16 lanes/node; uint2 gathers; x8 unroll
// (32 random lines in flight per wave — measured optimum) ----
__global__ void __launch_bounds__(256) k_agg(const unsigned int* __restrict__ hs,
                                             const int* __restrict__ rowptr,
                                             const int* __restrict__ csr_src,
                                             const float* __restrict__ dinv,
                                             const float* __restrict__ bias,
                                             unsigned int* __restrict__ h) {
    int wid = blockIdx.x * 4 + (threadIdx.x >> 6);
    int lane = threadIdx.x & 63;
    int q = lane >> 4;          // node within wave (0..3)
    int w = lane & 15;          // uint2 index within row: channels 4w..4w+3
    int node = wid * 4 + q;
    if (node >= N_NODES) return;
    const uint2* hp = (const uint2*)hs;  // row = 16 uint2
    uint2 sw = hp[(size_t)node * 16 + w];
    vf2 aA = unpack_bf2(sw.x), aB = unpack_bf2(sw.y);
    int k = rowptr[node], k1 = rowptr[node + 1];
    for (; k + 7 < k1; k += 8) {
        int s0 = csr_src[k],     s1 = csr_src[k + 1], s2 = csr_src[k + 2], s3 = csr_src[k + 3];
        int s4 = csr_src[k + 4], s5 = csr_src[k + 5], s6 = csr_src[k + 6], s7 = csr_src[k + 7];
        uint2 w0 = hp[(size_t)s0 * 16 + w];
        uint2 w1 = hp[(size_t)s1 * 16 + w];
        uint2 w2 = hp[(size_t)s2 * 16 + w];
        uint2 w3 = hp[(size_t)s3 * 16 + w];
        uint2 w4 = hp[(size_t)s4 * 16 + w];
        uint2 w5 = hp[(size_t)s5 * 16 + w];
        uint2 w6 = hp[(size_t)s6 * 16 + w];
        uint2 w7 = hp[(size_t)s7 * 16 + w];
        aA += ((unpack_bf2(w0.x) + unpack_bf2(w1.x)) + (unpack_bf2(w2.x) + unpack_bf2(w3.x)))
            + ((unpack_bf2(w4.x) + unpack_bf2(w5.x)) + (unpack_bf2(w6.x) + unpack_bf2(w7.x)));
        aB += ((unpack_bf2(w0.y) + unpack_bf2(w1.y)) + (unpack_bf2(w2.y) + unpack_bf2(w3.y)))
            + ((unpack_bf2(w4.y) + unpack_bf2(w5.y)) + (unpack_bf2(w6.y) + unpack_bf2(w7.y)));
    }
    for (; k + 3 < k1; k += 4) {
        int s0 = csr_src[k], s1 = csr_src[k + 1], s2 = csr_src[k + 2], s3 = csr_src[k + 3];
        uint2 w0 = hp[(size_t)s0 * 16 + w];
        uint2 w1 = hp[(size_t)s1 * 16 + w];
        uint2 w2 = hp[(size_t)s2 * 16 + w];
        uint2 w3 = hp[(size_t)s3 * 16 + w];
        aA += (unpack_bf2(w0.x) + unpack_bf2(w1.x)) + (unpack_bf2(w2.x) + unpack_bf2(w3.x));
        aB += (unpack_bf2(w0.y) + unpack_bf2(w1.y)) + (unpack_bf2(w2.y) + unpack_bf2(w3.y));
    }
    for (; k < k1; k++) {
        uint2 w0 = hp[(size_t)csr_src[k] * 16 + w];
        aA += unpack_bf2(w0.x);
        aB += unpack_bf2(w0.y);
    }
    float di = dinv[node];
    vf2 b0 = *(const vf2*)(bias + 4 * w);
    vf2 b1 = *(const vf2*)(bias + 4 * w + 2);
    float v0 = fmaxf(fmaf(aA.x, di, b0.x), 0.f);
    float v1 = fmaxf(fmaf(aA.y, di, b0.y), 0.f);
    float v2 = fmaxf(fmaf(aB.x, di, b1.x), 0.f);
    float v3 = fmaxf(fmaf(aB.y, di, b1.y), 0.f);
    uint2 ow; ow.x = pack2bf(v0, v1); ow.y = pack2bf(v2, v3);
    *(uint2*)(h + (size_t)node * 32 + 2 * w) = ow;
}

// ---- edge MLP: 8 lanes per edge-quad, direct per-lane index loads, packed-f32
// channel math (measured: ~53 µs, VGPR 36, occupancy 61%) ----
__global__ void __launch_bounds__(256) k_edge(const int* __restrict__ ei,
                       const unsigned int* __restrict__ P1, const unsigned int* __restrict__ P2,
                       const float* __restrict__ Wf, const int* __restrict__ flag,
                       void* __restrict__ out) {
    int tid = blockIdx.x * 256 + threadIdx.x;
    int g = tid >> 3;       // quad index: edges 4g .. 4g+3
    int k = tid & 7;        // sub-lane: channels j = 8k .. 8k+7
    int e0 = g * 4;
    if (e0 >= N_EDGES) return;  // N_EDGES % 4 == 0 -> e0..e0+3 all valid
    int f = flag[0];
    int r0 = load_row(ei, f, e0),     c0 = load_col(ei, f, e0);
    int r1 = load_row(ei, f, e0 + 1), c1 = load_col(ei, f, e0 + 1);
    int r2 = load_row(ei, f, e0 + 2), c2 = load_col(ei, f, e0 + 2);
    int r3 = load_row(ei, f, e0 + 3), c3 = load_col(ei, f, e0 + 3);
    // issue all 8 gathers before any compute
    uint4 ua0 = *(const uint4*)(P1 + (size_t)r0 * 32 + k * 4);
    uint4 ub0 = *(const uint4*)(P2 + (size_t)c0 * 32 + k * 4);
    uint4 ua1 = *(const uint4*)(P1 + (size_t)r1 * 32 + k * 4);
    uint4 ub1 = *(const uint4*)(P2 + (size_t)c1 * 32 + k * 4);
    uint4 ua2 = *(const uint4*)(P1 + (size_t)r2 * 32 + k * 4);
    uint4 ub2 = *(const uint4*)(P2 + (size_t)c2 * 32 + k * 4);
    uint4 ua3 = *(const uint4*)(P1 + (size_t)r3 * 32 + k * 4);
    uint4 ub3 = *(const uint4*)(P2 + (size_t)c3 * 32 + k * 4);
    // bias pairs and L2-weight pairs for this lane's 8 channels
    vf2 b2[4], wp[8];
#pragma unroll
    for (int t = 0; t < 4; t++) b2[t] = *(const vf2*)(Wf + WF_L1B + k * 8 + 2 * t);
#pragma unroll
    for (int t = 0; t < 8; t++) wp[t] = *(const vf2*)(Wf + WF_L2W + k * 16 + 2 * t);
    vf2 acc[4] = {{0.f, 0.f}, {0.f, 0.f}, {0.f, 0.f}, {0.f, 0.f}};
    auto edge_mlp = [&](const uint4& ua, const uint4& ub, int i) {
        unsigned int wa[4] = {ua.x, ua.y, ua.z, ua.w};
        unsigned int wb[4] = {ub.x, ub.y, ub.z, ub.w};
#pragma unroll
        for (int t = 0; t < 4; t++) {
            vf2 z = unpack_bf2(wa[t]) + unpack_bf2(wb[t]) + b2[t];
            z = __builtin_elementwise_max(z, (vf2){0.f, 0.f});
            acc[i] += z.x * wp[2 * t];      // (s0,s1) += z_ch0 * (w00,w01)
            acc[i] += z.y * wp[2 * t + 1];  // (s0,s1) += z_ch1 * (w10,w11)
        }
    };
    edge_mlp(ua0, ub0, 0);
    edge_mlp(ua1, ub1, 1);
    edge_mlp(ua2, ub2, 2);
    edge_mlp(ua3, ub3, 3);
    float s0[4], s1[4];
#pragma unroll
    for (int i = 0; i < 4; i++) { s0[i] = acc[i].x; s1[i] = acc[i].y; }
#pragma unroll
    for (int off = 1; off < 8; off <<= 1) {
#pragma unroll
        for (int i = 0; i < 4; i++) {
            s0[i] += __shfl_xor(s0[i], off);
            s1[i] += __shfl_xor(s1[i], off);
        }
    }
    if (k == 0) {
        float b0f = Wf[WF_L2B + 0], b1f = Wf[WF_L2B + 1];
        float z0[4], z1[4];
#pragma unroll
        for (int i = 0; i < 4; i++) {
            float za = s0[i] + b0f, zb = s1[i] + b1f;
            float m = fmaxf(za, zb);
            float lse = m + __logf(__expf(za - m) + __expf(zb - m));
            z0[i] = za - lse; z1[i] = zb - lse;
        }
        if (flag[1]) {
            uint4 v;
            v.x = pack2bf(z0[0], z1[0]); v.y = pack2bf(z0[1], z1[1]);
            v.z = pack2bf(z0[2], z1[2]); v.w = pack2bf(z0[3], z1[3]);
            *(uint4*)((unsigned int*)out + e0) = v;
        } else {
            float4 v01, v23;
            v01.x = z0[0]; v01.y = z1[0]; v01.z = z0[1]; v01.w = z1[1];
            v23.x = z0[2]; v23.y = z1[2]; v23.z = z0[3]; v23.w = z1[3];
            float4* op = (float4*)((float2*)out + e0);
            op[0] = v01;
            op[1] = v23;
        }
    }
}

extern "C" void kernel_launch(void* const* d_in, const int* in_sizes, int n_in,
                              void* d_out, int out_size, void* d_ws, size_t ws_size,
                              hipStream_t stream) {
    const void* x   = d_in[0];
    const int*  ei  = (const int*)d_in[1];

    char* ws = (char*)d_ws;
    constexpr size_t KB = 1024;

    int*   gcount = (int*)(ws);                    // 391 ints
    int*   bbase  = (int*)(ws + 8 * KB);           // 392 ints
    int*   flag   = (int*)(ws + 12 * KB);          // 8 B
    float* Wf     = (float*)(ws + 16 * KB);        // 83.2 KB -> ends ~99 KB
    float* dinv   = (float*)(ws + 400 * KB);       // 400 KB
    int*   rowptr = (int*)(ws + 800 * KB);         // 400 KB + 4
    unsigned int* tmp = (unsigned int*)(ws + 1300 * KB);  // 6400 KB -> ends 7700
    int*   csrsrc = (int*)(ws + 7700 * KB);        // 6400 KB -> ends 14100
    int*   bhist  = (int*)(ws + 14100 * KB);       // 392*391*4 = 0.6 MB
    int*   bofs   = (int*)(ws + 15400 * KB);       // 0.6 MB
    unsigned int* hs = (unsigned int*)(ws + 20500 * KB);  // 12800 KB (later P1)
    unsigned int* h  = (unsigned int*)(ws + 33300 * KB);  // 12800 KB (later P2)

    // detect + bucket-counter zero fused
    k_detect<<<SCAN_NB, 1024, 0, stream>>>(ei, (const unsigned int*)x, flag, gcount);
    k_prep<<<(WF_TOT + 255) / 256, 256, 0, stream>>>(d_in[2], d_in[4], d_in[6], d_in[3],
                                                     d_in[5], d_in[7], d_in[8], d_in[9],
                                                     flag, Wf);

    // bucketed CSR build: count -> fused scans -> LDS-sorted scatter -> sub-CSR
    k_bcount<<<NSCB, 256, 0, stream>>>(ei, flag, gcount, bhist);
    k_bscan2<<<NBUCK, 512, 0, stream>>>(gcount, bhist, bbase, bofs, rowptr);
    k_bscatter<<<NSCB, 512, 0, stream>>>(ei, flag, bofs, tmp);
    k_bcsr<<<NBUCK, 256, 0, stream>>>(tmp, bbase, rowptr, dinv, csrsrc);

    const int G = (N_NODES + 63) / 64;          // 1563 node groups
    const int gemm_blocks = (G * 2 + 3) / 4;    // 782

    // layer 1
    k_gemm_in_ws<<<gemm_blocks, 256, 0, stream>>>(x, Wf + WF_W1, dinv, hs, flag);
    k_agg<<<(N_NODES + 15) / 16, 256, 0, stream>>>(hs, rowptr, csrsrc, dinv, Wf + WF_B1, h);

    // layer 2
    k_gemm64_ws<<<gemm_blocks, 256, 0, stream>>>(h, Wf + WF_W2, dinv, hs);
    k_agg<<<(N_NODES + 15) / 16, 256, 0, stream>>>(hs, rowptr, csrsrc, dinv, Wf + WF_B2, h);

    // edge MLP: P1 -> hs, P2 in place on h (barrier-protected); original-order edge pass
    k_pair_ws<<<G, 256, 0, stream>>>(h, Wf + WF_L1W, hs);
    // 8 lanes per edge-quad -> 2 threads/edge -> 3.2M threads
    k_edge<<<(N_EDGES * 2 + 255) / 256, 256, 0, stream>>>(ei, hs, h, Wf, flag, d_out);
}